// Round 1
// baseline (2291.952 us; speedup 1.0000x reference)
//
#include <hip/hip_runtime.h>
#include <hip/hip_bf16.h>

#define B_   8
#define C_   128
#define H_   128
#define W_   128
#define HW_  16384
#define OC1  256
#define OC2  128

using bf16 = __hip_bfloat16;

// ---------------- K0: weight transpose to [k][oc] (oc contiguous) ------------
__global__ __launch_bounds__(256) void prep_weights(const float* __restrict__ w_off,
                                                    const float* __restrict__ w_conv,
                                                    float* __restrict__ wT_off,
                                                    float* __restrict__ wT_conv) {
  int idx = blockIdx.x * 256 + threadIdx.x;
  if (idx < 1152 * 256) {                 // w_off: (256 oc, 1152 k)
    int oc = idx & 255;
    int k  = idx >> 8;
    wT_off[k * OC1 + oc] = w_off[oc * 1152 + k];
  }
  if (idx < 1152 * 128) {                 // w_conv: (128 oc, 1152 k)
    int oc = idx & 127;
    int k  = idx >> 7;
    wT_conv[k * OC2 + oc] = w_conv[oc * 1152 + k];
  }
}

// ---------------- K1: offset conv 128->256, 3x3 pad 1, fp32 -> bf16 ----------
#define TJ1 32
__global__ __launch_bounds__(256) void conv_off(const float* __restrict__ x,
                                                const float* __restrict__ wT,
                                                bf16* __restrict__ offs) {
  __shared__ float tile[C_ * 3 * (TJ1 + 2)];       // [ic][r][col]
  const int jt = blockIdx.x, i = blockIdx.y, b = blockIdx.z;
  const int j0 = jt * TJ1;
  const int tid = threadIdx.x;
  const int TOT = C_ * 3 * (TJ1 + 2);              // 13056
  const float* xb = x + (size_t)b * C_ * HW_;
  for (int idx = tid; idx < TOT; idx += 256) {
    int ic  = idx / (3 * (TJ1 + 2));
    int rem = idx - ic * (3 * (TJ1 + 2));
    int r   = rem / (TJ1 + 2);
    int col = rem - r * (TJ1 + 2);
    int gi = i - 1 + r;
    int gj = j0 - 1 + col;
    float v = 0.f;
    if ((unsigned)gi < (unsigned)H_ && (unsigned)gj < (unsigned)W_)
      v = xb[ic * HW_ + gi * W_ + gj];
    tile[idx] = v;
  }
  __syncthreads();

  const int oc = tid;                               // 256 threads = 256 ocs
  float acc[TJ1];
#pragma unroll
  for (int t = 0; t < TJ1; ++t) acc[t] = 0.f;

  for (int ic = 0; ic < C_; ++ic) {
    const float* trow = &tile[ic * 3 * (TJ1 + 2)];
    const float* wrow = wT + (ic * 9) * OC1 + oc;
#pragma unroll
    for (int r = 0; r < 3; ++r) {
      float w0 = wrow[(r * 3 + 0) * OC1];
      float w1 = wrow[(r * 3 + 1) * OC1];
      float w2 = wrow[(r * 3 + 2) * OC1];
      const float* tr = trow + r * (TJ1 + 2);
#pragma unroll
      for (int t = 0; t < TJ1; ++t)
        acc[t] += w0 * tr[t] + w1 * tr[t + 1] + w2 * tr[t + 2];
    }
  }

  bf16* op = offs + ((size_t)(b * OC1 + oc)) * HW_ + i * W_ + j0;
#pragma unroll
  for (int t = 0; t < TJ1; ++t) op[t] = __float2bfloat16(acc[t]);
}

// ---------------- K2: deform bilinear sampling (quirky reshape semantics) ----
__global__ __launch_bounds__(256) void deform(const float* __restrict__ x,
                                              const bf16* __restrict__ offs,
                                              bf16* __restrict__ xoff) {
  int gid = blockIdx.x * 256 + threadIdx.x;        // 16,777,216 total
  int q  = gid & (HW_ - 1);
  int pc = gid >> 14;                              // b*128 + c
  int i = q >> 7, j = q & (W_ - 1);

  // flat-within-batch index c*32768 + 2q (+1): contiguous bf16 pair
  const bf16* op = offs + ((size_t)pc << 15) + 2 * q;
  float oy = __bfloat162float(op[0]);
  float ox = __bfloat162float(op[1]);

  float yc = fminf(fmaxf(oy + (float)i, 0.f), 127.f);
  float xc = fminf(fmaxf(ox + (float)j, 0.f), 127.f);
  float y0f = floorf(yc), y1f = ceilf(yc);
  float x0f = floorf(xc), x1f = ceilf(xc);
  int y0 = (int)y0f, y1 = (int)y1f, x0 = (int)x0f, x1 = (int)x1f;

  const float* img = x + ((size_t)pc << 14);
  float v_lt = img[y0 * W_ + x0];
  float v_rb = img[y1 * W_ + x1];
  float v_lb = img[y0 * W_ + x1];
  float v_rt = img[y1 * W_ + x0];
  float dy = yc - y0f, dx = xc - x0f;
  float v_t = v_lt + (v_rt - v_lt) * dy;
  float v_b = v_lb + (v_rb - v_lb) * dy;
  float o   = v_t + (v_b - v_t) * dx;
  xoff[gid] = __float2bfloat16(o);
}

// ---------------- K3: main conv 128->128, 3x3 pad 1 + bias + relu -> fp32 ----
#define TJ3 32
__global__ __launch_bounds__(256) void conv_main(const bf16* __restrict__ xoff,
                                                 const float* __restrict__ wT,
                                                 const float* __restrict__ bias,
                                                 float* __restrict__ out) {
  __shared__ float tile[C_ * 3 * (TJ3 + 2)];
  const int jt = blockIdx.x, i = blockIdx.y, b = blockIdx.z;
  const int j0 = jt * TJ3;
  const int tid = threadIdx.x;
  const int TOT = C_ * 3 * (TJ3 + 2);
  const bf16* xb = xoff + (size_t)b * C_ * HW_;
  for (int idx = tid; idx < TOT; idx += 256) {
    int ic  = idx / (3 * (TJ3 + 2));
    int rem = idx - ic * (3 * (TJ3 + 2));
    int r   = rem / (TJ3 + 2);
    int col = rem - r * (TJ3 + 2);
    int gi = i - 1 + r;
    int gj = j0 - 1 + col;
    float v = 0.f;
    if ((unsigned)gi < (unsigned)H_ && (unsigned)gj < (unsigned)W_)
      v = __bfloat162float(xb[ic * HW_ + gi * W_ + gj]);
    tile[idx] = v;
  }
  __syncthreads();

  const int oc = tid & 127;
  const int jh = tid >> 7;                          // column half: 0 or 1
  float acc[16];
#pragma unroll
  for (int t = 0; t < 16; ++t) acc[t] = 0.f;

  for (int ic = 0; ic < C_; ++ic) {
    const float* trow = &tile[ic * 3 * (TJ3 + 2) + jh * 16];
    const float* wrow = wT + (ic * 9) * OC2 + oc;
#pragma unroll
    for (int r = 0; r < 3; ++r) {
      float w0 = wrow[(r * 3 + 0) * OC2];
      float w1 = wrow[(r * 3 + 1) * OC2];
      float w2 = wrow[(r * 3 + 2) * OC2];
      const float* tr = trow + r * (TJ3 + 2);
#pragma unroll
      for (int t = 0; t < 16; ++t)
        acc[t] += w0 * tr[t] + w1 * tr[t + 1] + w2 * tr[t + 2];
    }
  }

  float bv = bias[oc];
  float* op = out + ((size_t)(b * OC2 + oc)) * HW_ + i * W_ + j0 + jh * 16;
#pragma unroll
  for (int t = 0; t < 16; ++t) {
    float v = acc[t] + bv;
    op[t] = v > 0.f ? v : 0.f;
  }
}

// ---------------- K4: BN batch stats (one block per channel) -----------------
__global__ __launch_bounds__(256) void bn_stats(const float* __restrict__ y,
                                                const float* __restrict__ gamma,
                                                const float* __restrict__ beta,
                                                float* __restrict__ stats) {
  int c = blockIdx.x;
  float s = 0.f, s2 = 0.f;
  for (int b = 0; b < B_; ++b) {
    const float* p = y + ((size_t)(b * C_ + c) << 14);
    for (int idx = threadIdx.x; idx < HW_; idx += 256) {
      float v = p[idx];
      s += v;
      s2 += v * v;
    }
  }
#pragma unroll
  for (int off = 32; off > 0; off >>= 1) {
    s  += __shfl_down(s, off);
    s2 += __shfl_down(s2, off);
  }
  __shared__ float ls[8];
  int wid = threadIdx.x >> 6;
  if ((threadIdx.x & 63) == 0) { ls[wid] = s; ls[4 + wid] = s2; }
  __syncthreads();
  if (threadIdx.x == 0) {
    s  = ls[0] + ls[1] + ls[2] + ls[3];
    s2 = ls[4] + ls[5] + ls[6] + ls[7];
    const float invn = 1.f / (float)(B_ * HW_);
    float mean = s * invn;
    float var  = s2 * invn - mean * mean;
    float inv  = rsqrtf(var + 1e-5f);
    float sc = gamma[c] * inv;
    stats[c]        = sc;
    stats[C_ + c]   = beta[c] - mean * sc;
  }
}

// ---------------- K5: apply BN affine in place (float4) ----------------------
__global__ __launch_bounds__(256) void bn_apply(float* __restrict__ y,
                                                const float* __restrict__ stats) {
  int gid = blockIdx.x * 256 + threadIdx.x;        // over 4,194,304 float4s
  int c = (gid >> 12) & 127;
  float sc = stats[c], sh = stats[C_ + c];
  float4 v = ((float4*)y)[gid];
  v.x = v.x * sc + sh;
  v.y = v.y * sc + sh;
  v.z = v.z * sc + sh;
  v.w = v.w * sc + sh;
  ((float4*)y)[gid] = v;
}

// ---------------- launch -----------------------------------------------------
extern "C" void kernel_launch(void* const* d_in, const int* in_sizes, int n_in,
                              void* d_out, int out_size, void* d_ws, size_t ws_size,
                              hipStream_t stream) {
  const float* x      = (const float*)d_in[0];
  const float* w_off  = (const float*)d_in[1];
  const float* w_conv = (const float*)d_in[2];
  const float* b_conv = (const float*)d_in[3];
  const float* gamma  = (const float*)d_in[4];
  const float* beta   = (const float*)d_in[5];
  float* out = (float*)d_out;

  char* ws = (char*)d_ws;
  bf16*  offs    = (bf16*)ws;                        // 33,554,432 bf16 = 64 MiB
  bf16*  xoff    = (bf16*)(ws + 67108864);           // 16,777,216 bf16 = 32 MiB
  float* wT_off  = (float*)(ws + 100663296);         // 294,912 fp32
  float* wT_conv = (float*)(ws + 101842944);         // 147,456 fp32
  float* stats   = (float*)(ws + 102432768);         // 256 fp32

  prep_weights<<<1152, 256, 0, stream>>>(w_off, w_conv, wT_off, wT_conv);
  conv_off   <<<dim3(W_ / TJ1, H_, B_), 256, 0, stream>>>(x, wT_off, offs);
  deform     <<<(B_ * C_ * HW_) / 256, 256, 0, stream>>>(x, offs, xoff);
  conv_main  <<<dim3(W_ / TJ3, H_, B_), 256, 0, stream>>>(xoff, wT_conv, b_conv, out);
  bn_stats   <<<C_, 256, 0, stream>>>(out, gamma, beta, stats);
  bn_apply   <<<(B_ * C_ * HW_) / (4 * 256), 256, 0, stream>>>(out, stats);
}

// Round 2
// 455.022 us; speedup vs baseline: 5.0370x; 5.0370x over previous
//
#include <hip/hip_runtime.h>

#define B_   8
#define C_   128
#define H_   128
#define W_   128
#define HW_  16384

typedef short v8s __attribute__((ext_vector_type(8)));
typedef float v4f __attribute__((ext_vector_type(4)));

__device__ __forceinline__ float bf2f(unsigned short u) {
  unsigned int v = ((unsigned int)u) << 16;
  float f; __builtin_memcpy(&f, &v, 4); return f;
}
__device__ __forceinline__ unsigned short f2us(float f) {
  unsigned int u; __builtin_memcpy(&u, &f, 4);
  u += 0x7fffu + ((u >> 16) & 1u);           // RNE
  return (unsigned short)(u >> 16);
}

// ---------------- pack weights into MFMA A-fragment order --------------------
// pack[cc][pp][g][l][j] : oc=g*16+(l&15), kk=(l>>4)*8+j, ic=cc*16+(kk&15),
// rs=pp*2+(kk>>4); rs==9 -> 0 (pad). 1KB per (cc,pp,g) block = one wave load.
__global__ __launch_bounds__(256) void pack_w(const float* __restrict__ w,
                                              unsigned short* __restrict__ pack,
                                              int G) {
  int idx = blockIdx.x * 256 + threadIdx.x;
  if (idx >= 20480 * G) return;
  int j  = idx & 7;
  int l  = (idx >> 3) & 63;
  int g  = (idx >> 9) % G;
  int t2 = idx / (512 * G);
  int pp = t2 % 5;
  int cc = t2 / 5;
  int oc = g * 16 + (l & 15);
  int kk = ((l >> 4) << 3) + j;
  int ic = (cc << 4) + (kk & 15);
  int rs = pp * 2 + (kk >> 4);
  float v = (rs < 9) ? w[(oc * C_ + ic) * 9 + rs] : 0.f;
  pack[idx] = f2us(v);
}

// ---------------- transpose x: fp32 [b][c][i][j] -> bf16 [b][i][j][c] --------
__global__ __launch_bounds__(256) void transpose_x(const float* __restrict__ x,
                                                   unsigned short* __restrict__ xt) {
  __shared__ alignas(16) unsigned short t[32 * 132];
  const int j0 = blockIdx.x * 32, i = blockIdx.y, b = blockIdx.z;
  const int tid = threadIdx.x;
  for (int e = tid; e < 128 * 32; e += 256) {
    int c = e >> 5, jj = e & 31;
    float v = x[((b * C_ + c) * H_ + i) * W_ + j0 + jj];
    t[jj * 132 + c] = f2us(v);
  }
  __syncthreads();
  for (int e = tid; e < 32 * 32; e += 256) {
    int c4 = (e & 31) << 2, jj = e >> 5;
    uint2 v = *(const uint2*)&t[jj * 132 + c4];
    *(uint2*)(xt + ((b * H_ + i) * W_ + j0 + jj) * C_ + c4) = v;
  }
}

// ---------------- implicit-GEMM conv via MFMA --------------------------------
// MODE 0: plain bf16 store (offset conv, OC=G*16). MODE 1: +bias+relu+BN partials.
template <int MODE, int G>
__global__ __launch_bounds__(256) void conv_gemm(const unsigned short* __restrict__ xt,
                                                 const unsigned short* __restrict__ pack,
                                                 const float* __restrict__ bias,
                                                 unsigned short* __restrict__ outp,
                                                 float* __restrict__ ps) {
  __shared__ uint4 raw4[1170];                       // 3*130 cols * 48B
  __shared__ float bs1[128], bs2[128];
  char* raw = (char*)raw4;

  const int nb = blockIdx.x;                          // b*128 + i
  const int b = nb >> 7, i = nb & 127;
  const int mt = blockIdx.y;
  const int tid  = threadIdx.x;
  const int lane = tid & 63, wid = tid >> 6;
  const int q = lane >> 4, n = lane & 15;
  const int wm = wid & 1, wn = wid >> 1;

  if (MODE == 1 && tid < 128) { bs1[tid] = 0.f; bs2[tid] = 0.f; }

  // per-lane LDS byte-offset base per rs-pair pp
  int boff[5];
#pragma unroll
  for (int pp = 0; pp < 5; ++pp) {
    int rs = pp * 2 + (q >> 1);
    if (rs > 8) rs = 8;                               // pad half: A is zero there
    int r = (rs >= 6) ? 2 : ((rs >= 3) ? 1 : 0);
    int s = rs - r * 3;
    boff[pp] = (r * 130 + s) * 48 + (q & 1) * 16;
  }
  const int pcol = (wn * 64 + n) * 48;

  v4f acc[4][4];
#pragma unroll
  for (int a = 0; a < 4; ++a)
#pragma unroll
    for (int c = 0; c < 4; ++c) acc[a][c] = (v4f){0.f, 0.f, 0.f, 0.f};

  const v8s* packv = (const v8s*)pack;
  const int gbase = mt * 8 + wm * 4;

  for (int cc = 0; cc < 8; ++cc) {
    __syncthreads();
    // stage halo window: rawX[3 rows][130 cols][16 ic] bf16, 48B col stride
    for (int u = tid; u < 780; u += 256) {
      int half = u & 1, rc = u >> 1;
      int r = rc / 130, c = rc - r * 130;
      int ii = i + r - 1, jj = c - 1;
      uint4 v = {0u, 0u, 0u, 0u};
      if ((unsigned)ii < 128u && (unsigned)jj < 128u)
        v = *(const uint4*)(xt + ((b * H_ + ii) * W_ + jj) * C_ + cc * 16 + half * 8);
      *(uint4*)(raw + rc * 48 + half * 16) = v;
    }
    __syncthreads();

    v8s Acur[4];
    {
      const v8s* ap = packv + ((cc * 5 + 0) * G + gbase) * 64 + lane;
#pragma unroll
      for (int fm = 0; fm < 4; ++fm) Acur[fm] = ap[fm * 64];
    }
#pragma unroll
    for (int pp = 0; pp < 5; ++pp) {
      v8s Anxt[4];
      if (pp < 4) {
        const v8s* ap = packv + ((cc * 5 + pp + 1) * G + gbase) * 64 + lane;
#pragma unroll
        for (int fm = 0; fm < 4; ++fm) Anxt[fm] = ap[fm * 64];
      }
      v8s Bf[4];
#pragma unroll
      for (int fn = 0; fn < 4; ++fn)
        Bf[fn] = *(const v8s*)(raw + boff[pp] + pcol + fn * (16 * 48));
#pragma unroll
      for (int fm = 0; fm < 4; ++fm) {
#pragma unroll
        for (int fn = 0; fn < 4; ++fn)
          acc[fm][fn] = __builtin_amdgcn_mfma_f32_16x16x32_bf16(Acur[fm], Bf[fn],
                                                                acc[fm][fn], 0, 0, 0);
      }
      if (pp < 4) {
#pragma unroll
        for (int fm = 0; fm < 4; ++fm) Acur[fm] = Anxt[fm];
      }
    }
  }

  // epilogue: D element (fm,fn,rr): oc = mt*128+wm*64+fm*16+q*4+rr, px = wn*64+fn*16+n
  const int OC = G * 16;
  const int ob = (b * OC + mt * 128 + wm * 64) * HW_ + i * W_ + wn * 64;

  if (MODE == 0) {
#pragma unroll
    for (int fm = 0; fm < 4; ++fm)
#pragma unroll
      for (int fn = 0; fn < 4; ++fn)
#pragma unroll
        for (int rr = 0; rr < 4; ++rr)
          outp[ob + (fm * 16 + q * 4 + rr) * HW_ + fn * 16 + n] = f2us(acc[fm][fn][rr]);
  } else {
    float bv[4][4], s1a[4][4], s2a[4][4];
#pragma unroll
    for (int fm = 0; fm < 4; ++fm)
#pragma unroll
      for (int rr = 0; rr < 4; ++rr) {
        bv[fm][rr] = bias[wm * 64 + fm * 16 + q * 4 + rr];
        s1a[fm][rr] = 0.f; s2a[fm][rr] = 0.f;
      }
#pragma unroll
    for (int fm = 0; fm < 4; ++fm)
#pragma unroll
      for (int fn = 0; fn < 4; ++fn)
#pragma unroll
        for (int rr = 0; rr < 4; ++rr) {
          float v = acc[fm][fn][rr] + bv[fm][rr];
          v = fmaxf(v, 0.f);
          outp[ob + (fm * 16 + q * 4 + rr) * HW_ + fn * 16 + n] = f2us(v);
          s1a[fm][rr] += v; s2a[fm][rr] += v * v;
        }
#pragma unroll
    for (int fm = 0; fm < 4; ++fm)
#pragma unroll
      for (int rr = 0; rr < 4; ++rr) {
        float s1 = s1a[fm][rr], s2 = s2a[fm][rr];
#pragma unroll
        for (int m = 1; m < 16; m <<= 1) {
          s1 += __shfl_xor(s1, m);
          s2 += __shfl_xor(s2, m);
        }
        if (n == 0) {
          atomicAdd(&bs1[wm * 64 + fm * 16 + q * 4 + rr], s1);
          atomicAdd(&bs2[wm * 64 + fm * 16 + q * 4 + rr], s2);
        }
      }
    __syncthreads();
    if (tid < 128) {
      ps[nb * 128 + tid]          = bs1[tid];
      ps[131072 + nb * 128 + tid] = bs2[tid];
    }
  }
}

// ---------------- deform + fused transpose -----------------------------------
__global__ __launch_bounds__(256) void deform_t(const float* __restrict__ x,
                                                const unsigned short* __restrict__ offs,
                                                unsigned short* __restrict__ xofft) {
  __shared__ alignas(16) unsigned short t[128 * 132];
  const int i = blockIdx.x, b = blockIdx.y;
  const int tid = threadIdx.x;
  for (int e = tid; e < 16384; e += 256) {
    int c = e >> 7, j = e & 127;
    int qpix = (i << 7) + j;
    int oidx = (b << 22) + (c << 15) + 2 * qpix;     // quirky reshape semantics
    float oy = bf2f(offs[oidx]);
    float ox = bf2f(offs[oidx + 1]);
    float yc = fminf(fmaxf(oy + (float)i, 0.f), 127.f);
    float xc = fminf(fmaxf(ox + (float)j, 0.f), 127.f);
    float y0f = floorf(yc), y1f = ceilf(yc);
    float x0f = floorf(xc), x1f = ceilf(xc);
    int y0 = (int)y0f, y1 = (int)y1f, x0 = (int)x0f, x1 = (int)x1f;
    const float* img = x + ((b * C_ + c) << 14);
    float v_lt = img[y0 * W_ + x0];
    float v_rb = img[y1 * W_ + x1];
    float v_lb = img[y0 * W_ + x1];
    float v_rt = img[y1 * W_ + x0];
    float dy = yc - y0f, dx = xc - x0f;
    float v_t = v_lt + (v_rt - v_lt) * dy;
    float v_b = v_lb + (v_rb - v_lb) * dy;
    float o   = v_t + (v_b - v_t) * dx;
    t[j * 132 + c] = f2us(o);
  }
  __syncthreads();
  for (int e = tid; e < 4096; e += 256) {
    int c4 = (e & 31) << 2, j = e >> 5;
    uint2 v = *(const uint2*)&t[j * 132 + c4];
    *(uint2*)(xofft + ((b * H_ + i) * W_ + j) * C_ + c4) = v;
  }
}

// ---------------- BN finalize: fold stats into scale/shift -------------------
__global__ __launch_bounds__(256) void bn_finalize(const float* __restrict__ ps,
                                                   const float* __restrict__ gamma,
                                                   const float* __restrict__ beta,
                                                   float* __restrict__ stats) {
  const int c = blockIdx.x, tid = threadIdx.x;
  float s1 = 0.f, s2 = 0.f;
  for (int k = tid; k < 1024; k += 256) {
    s1 += ps[k * 128 + c];
    s2 += ps[131072 + k * 128 + c];
  }
#pragma unroll
  for (int m = 32; m > 0; m >>= 1) {
    s1 += __shfl_down(s1, m);
    s2 += __shfl_down(s2, m);
  }
  __shared__ float l1[4], l2[4];
  int wid = tid >> 6;
  if ((tid & 63) == 0) { l1[wid] = s1; l2[wid] = s2; }
  __syncthreads();
  if (tid == 0) {
    s1 = l1[0] + l1[1] + l1[2] + l1[3];
    s2 = l2[0] + l2[1] + l2[2] + l2[3];
    const float invn = 1.f / 131072.f;
    float mean = s1 * invn;
    float var  = s2 * invn - mean * mean;
    float inv  = rsqrtf(var + 1e-5f);
    float sc = gamma[c] * inv;
    stats[c]       = sc;
    stats[128 + c] = beta[c] - mean * sc;
  }
}

// ---------------- BN apply: bf16 y -> fp32 out -------------------------------
__global__ __launch_bounds__(256) void bn_apply(const unsigned short* __restrict__ y,
                                                const float* __restrict__ stats,
                                                float* __restrict__ out) {
  int gid = blockIdx.x * 256 + threadIdx.x;          // 2,097,152 threads x 8 elems
  int base = gid << 3;
  int c = (base >> 14) & 127;
  float sc = stats[c], sh = stats[128 + c];
  uint4 u = *(const uint4*)(y + base);
  const unsigned short* us = (const unsigned short*)&u;
  float4 o0, o1;
  o0.x = bf2f(us[0]) * sc + sh;  o0.y = bf2f(us[1]) * sc + sh;
  o0.z = bf2f(us[2]) * sc + sh;  o0.w = bf2f(us[3]) * sc + sh;
  o1.x = bf2f(us[4]) * sc + sh;  o1.y = bf2f(us[5]) * sc + sh;
  o1.z = bf2f(us[6]) * sc + sh;  o1.w = bf2f(us[7]) * sc + sh;
  ((float4*)out)[gid * 2]     = o0;
  ((float4*)out)[gid * 2 + 1] = o1;
}

// ---------------- launch -----------------------------------------------------
extern "C" void kernel_launch(void* const* d_in, const int* in_sizes, int n_in,
                              void* d_out, int out_size, void* d_ws, size_t ws_size,
                              hipStream_t stream) {
  const float* x      = (const float*)d_in[0];
  const float* w_off  = (const float*)d_in[1];
  const float* w_conv = (const float*)d_in[2];
  const float* b_conv = (const float*)d_in[3];
  const float* gamma  = (const float*)d_in[4];
  const float* beta   = (const float*)d_in[5];
  float* out = (float*)d_out;

  char* ws = (char*)d_ws;
  // region A [0,32M): x_t, later xoff_t (x_t dead after conv_off)
  unsigned short* x_t    = (unsigned short*)ws;
  unsigned short* xoff_t = (unsigned short*)ws;
  // region B [32M,96M): offs; yws aliases first half after deform
  unsigned short* offs = (unsigned short*)(ws + 33554432);
  unsigned short* yws  = (unsigned short*)(ws + 33554432);
  // ps/stats reuse [64M,96M) after offs is dead
  float* ps    = (float*)(ws + 67108864);
  float* stats = (float*)(ws + 68157440);
  // packs live outside everything (~96M..101.6M, within proven footprint)
  unsigned short* pack_off  = (unsigned short*)(ws + 100663296);
  unsigned short* pack_main = (unsigned short*)(ws + 101318656);

  pack_w<<<80 * 16, 256, 0, stream>>>(w_off, pack_off, 16);
  pack_w<<<80 * 8, 256, 0, stream>>>(w_conv, pack_main, 8);
  transpose_x<<<dim3(4, 128, 8), 256, 0, stream>>>(x, x_t);
  conv_gemm<0, 16><<<dim3(1024, 2), 256, 0, stream>>>(x_t, pack_off, nullptr, offs, nullptr);
  deform_t<<<dim3(128, 8), 256, 0, stream>>>(x, offs, xoff_t);
  conv_gemm<1, 8><<<dim3(1024, 1), 256, 0, stream>>>(xoff_t, pack_main, b_conv, yws, ps);
  bn_finalize<<<128, 256, 0, stream>>>(ps, gamma, beta, stats);
  bn_apply<<<8192, 256, 0, stream>>>(yws, stats, out);
}